// Round 1
// baseline (587.386 us; speedup 1.0000x reference)
//
#include <hip/hip_runtime.h>

// x: [B=16, C=64, H=256, W=256] fp32
// w: [1, 2, 3, 3] fp32  (in-ch 0 = max-pool, 1 = avg-pool; cross-correlation)
// out = sigmoid(conv2d(concat([max_c x, mean_c x]), w, SAME)) * x
//
// Fused single kernel: one block = 16x16 spatial tile of one batch.
// Each thread keeps its 64-channel column in registers (read x from HBM once),
// pools in-register, LDS holds the 18x18 pooled halo tile for the 3x3 conv.

#define TILE 16

__global__ __launch_bounds__(256) void spatial_attn_fused(
    const float* __restrict__ x,
    const float* __restrict__ wgt,
    float* __restrict__ out)
{
    constexpr int C = 64, H = 256, W = 256;
    const int b  = blockIdx.z;
    const int th = blockIdx.y * TILE;   // tile origin (h)
    const int tw = blockIdx.x * TILE;   // tile origin (w)

    const int tid = threadIdx.x;
    const int py  = tid >> 4;           // 0..15
    const int px  = tid & 15;           // 0..15
    const int h   = th + py;
    const int w   = tw + px;

    // pooled tile with 1-pixel halo; +3 pad on inner dim to soften bank aliasing
    __shared__ float smax[TILE + 2][TILE + 3];
    __shared__ float savg[TILE + 2][TILE + 3];

    const size_t cstride = (size_t)H * W;                      // 65536
    const size_t idx0    = ((size_t)(b * C) * H + h) * W + w;  // channel 0 of this pixel

    // ---- interior: load 64-channel column into registers, pool ----
    float xv[C];
    float mx = -INFINITY, sum = 0.0f;
#pragma unroll
    for (int c = 0; c < C; ++c) {
        float v = x[idx0 + (size_t)c * cstride];
        xv[c] = v;
        mx = fmaxf(mx, v);
        sum += v;
    }
    smax[py + 1][px + 1] = mx;
    savg[py + 1][px + 1] = sum * (1.0f / 64.0f);

    // ---- halo ring: 68 pixels of the 18x18 pooled tile, re-pooled ----
    if (tid < 68) {
        int hy, hx;
        if (tid < 18)      { hy = 0;              hx = tid;       }
        else if (tid < 36) { hy = TILE + 1;       hx = tid - 18;  }
        else if (tid < 52) { hy = 1 + (tid - 36); hx = 0;         }
        else               { hy = 1 + (tid - 52); hx = TILE + 1;  }
        const int gh = th + hy - 1;
        const int gw = tw + hx - 1;
        float hmx = 0.0f, hav = 0.0f;   // zero-padding outside the image
        if (gh >= 0 && gh < H && gw >= 0 && gw < W) {
            const size_t hidx = ((size_t)(b * C) * H + gh) * W + gw;
            float m2 = -INFINITY, s2 = 0.0f;
#pragma unroll 8
            for (int c = 0; c < C; ++c) {
                float v = x[hidx + (size_t)c * cstride];
                m2 = fmaxf(m2, v);
                s2 += v;
            }
            hmx = m2;
            hav = s2 * (1.0f / 64.0f);
        }
        smax[hy][hx] = hmx;
        savg[hy][hx] = hav;
    }
    __syncthreads();

    // ---- 3x3 conv (cross-correlation) + sigmoid ----
    // wgt layout [1][2][3][3]: wgt[(ci*3+kh)*3+kw], ci=0 -> max, ci=1 -> avg
    float acc = 0.0f;
#pragma unroll
    for (int kh = 0; kh < 3; ++kh) {
#pragma unroll
        for (int kw = 0; kw < 3; ++kw) {
            acc += wgt[(0 * 3 + kh) * 3 + kw] * smax[py + kh][px + kw];
            acc += wgt[(1 * 3 + kh) * 3 + kw] * savg[py + kh][px + kw];
        }
    }
    const float attn = 1.0f / (1.0f + __expf(-acc));

    // ---- broadcast multiply from register-held column ----
#pragma unroll
    for (int c = 0; c < C; ++c) {
        out[idx0 + (size_t)c * cstride] = attn * xv[c];
    }
}

extern "C" void kernel_launch(void* const* d_in, const int* in_sizes, int n_in,
                              void* d_out, int out_size, void* d_ws, size_t ws_size,
                              hipStream_t stream) {
    const float* x   = (const float*)d_in[0];
    const float* wgt = (const float*)d_in[1];
    float* out = (float*)d_out;

    dim3 grid(256 / TILE, 256 / TILE, 16);  // (w-tiles, h-tiles, batch)
    dim3 block(256);
    spatial_attn_fused<<<grid, block, 0, stream>>>(x, wgt, out);
}

// Round 2
// 487.770 us; speedup vs baseline: 1.2042x; 1.2042x over previous
//
#include <hip/hip_runtime.h>

// x: [B=16, C=64, H=256, W=256] fp32
// out = sigmoid(conv3x3(concat([max_c x, mean_c x]), w, SAME)) * x
//
// Fused single-pass: block = 32x8 spatial tile (wave = 2 rows x 32 cols =
// 2 full 128B lines per channel access). Each thread holds its 64-channel
// column in VGPRs (pinned via empty asm so the compiler cannot re-load x
// after the barrier), pools in-register; 10x34 pooled halo tile in LDS
// feeds the 3x3 conv; multiply reuses the pinned registers.

#define TW 32
#define TH 8

__global__ __launch_bounds__(256) void spatial_attn_fused(
    const float* __restrict__ x,
    const float* __restrict__ wgt,
    float* __restrict__ out)
{
    constexpr int C = 64, H = 256, W = 256;
    const int b  = blockIdx.z;
    const int th = blockIdx.y * TH;
    const int tw = blockIdx.x * TW;

    const int tid = threadIdx.x;
    const int py  = tid >> 5;          // 0..7
    const int px  = tid & 31;          // 0..31
    const int h   = th + py;
    const int w   = tw + px;

    __shared__ float smax[TH + 2][TW + 3];   // +3 pad on inner dim
    __shared__ float savg[TH + 2][TW + 3];

    const size_t cstride = (size_t)H * W;                      // 65536
    const size_t idx0    = ((size_t)(b * C) * H + h) * W + w;

    // ---- interior: 64-channel column -> registers, pool in-register ----
    float xv[C];
    float mx = -INFINITY, sum = 0.0f;
#pragma unroll
    for (int c = 0; c < C; ++c) {
        float v = x[idx0 + (size_t)c * cstride];
        xv[c] = v;
        mx = fmaxf(mx, v);
        sum += v;
    }
    // Pin the column in VGPRs: forbids rematerializing the x loads after
    // the barrier (round-1 compiler sank them -> x read twice from HBM).
#pragma unroll
    for (int c = 0; c < C; ++c) asm volatile("" : "+v"(xv[c]));

    smax[py + 1][px + 1] = mx;
    savg[py + 1][px + 1] = sum * (1.0f / 64.0f);

    // ---- halo ring: 84 pixels of the 10x34 pooled tile ----
    if (tid < 2 * (TW + 2) + 2 * TH) {   // 84
        int hy, hx;
        if (tid < TW + 2)          { hy = 0;                       hx = tid;            }
        else if (tid < 2*(TW + 2)) { hy = TH + 1;                  hx = tid - (TW + 2); }
        else if (tid < 2*(TW+2)+TH){ hy = 1 + (tid - 2*(TW + 2));  hx = 0;              }
        else                       { hy = 1 + (tid - 2*(TW+2)-TH); hx = TW + 1;         }
        const int gh = th + hy - 1;
        const int gw = tw + hx - 1;
        float hmx = 0.0f, hav = 0.0f;    // zero-padding outside the image
        if (gh >= 0 && gh < H && gw >= 0 && gw < W) {
            const size_t hidx = ((size_t)(b * C) * H + gh) * W + gw;
            float m2 = -INFINITY, s2 = 0.0f;
#pragma unroll 8
            for (int c = 0; c < C; ++c) {
                float v = x[hidx + (size_t)c * cstride];
                m2 = fmaxf(m2, v);
                s2 += v;
            }
            hmx = m2;
            hav = s2 * (1.0f / 64.0f);
        }
        smax[hy][hx] = hmx;
        savg[hy][hx] = hav;
    }
    __syncthreads();

    // ---- 3x3 conv (cross-correlation) + sigmoid ----
    // wgt [1][2][3][3]: ci=0 -> max branch, ci=1 -> avg branch
    float acc = 0.0f;
#pragma unroll
    for (int kh = 0; kh < 3; ++kh) {
#pragma unroll
        for (int kw = 0; kw < 3; ++kw) {
            acc += wgt[(0 * 3 + kh) * 3 + kw] * smax[py + kh][px + kw];
            acc += wgt[(1 * 3 + kh) * 3 + kw] * savg[py + kh][px + kw];
        }
    }
    const float attn = 1.0f / (1.0f + __expf(-acc));

    // ---- broadcast multiply from the pinned register column ----
#pragma unroll
    for (int c = 0; c < C; ++c) {
        out[idx0 + (size_t)c * cstride] = attn * xv[c];
    }
}

extern "C" void kernel_launch(void* const* d_in, const int* in_sizes, int n_in,
                              void* d_out, int out_size, void* d_ws, size_t ws_size,
                              hipStream_t stream) {
    const float* x   = (const float*)d_in[0];
    const float* wgt = (const float*)d_in[1];
    float* out = (float*)d_out;

    dim3 grid(256 / TW, 256 / TH, 16);   // (w-tiles=8, h-tiles=32, batch=16)
    dim3 block(256);
    spatial_attn_fused<<<grid, block, 0, stream>>>(x, wgt, out);
}